// Round 23
// baseline (156.833 us; speedup 1.0000x reference)
//
#include <hip/hip_runtime.h>
#include <hip/hip_bf16.h>
#include <stdint.h>

typedef short bf16x8 __attribute__((ext_vector_type(8)));
typedef float f32x4 __attribute__((ext_vector_type(4)));
typedef float f32x16 __attribute__((ext_vector_type(16)));
typedef unsigned int uint4v __attribute__((ext_vector_type(4)));

#define NB 4
#define NL 2048
#define ND 1024
#define NH 16
#define NDK 64
#define NM (NB*NL)
// 1/sqrt(DK) * log2(e): folded into Q at the QKV-GEMM epilogue -> softmax in exp2 domain
#define QSCALE 0.18033688011112042f

__device__ __forceinline__ ushort f2bf(float f) {
  __bf16 h = (__bf16)f;
  return __builtin_bit_cast(unsigned short, h);
}

__device__ __forceinline__ unsigned int cvtpk(float lo, float hi) {
  unsigned int d;
  asm("v_cvt_pk_bf16_f32 %0, %1, %2" : "=v"(d) : "v"(lo), "v"(hi));
  return d;
}

// async global->LDS, 16B per lane. lds base must be wave-uniform; HW adds lane*16.
__device__ __forceinline__ void gload16(const void* g, void* l) {
  __builtin_amdgcn_global_load_lds(
      (__attribute__((address_space(1))) void*)(uintptr_t)g,
      (__attribute__((address_space(3))) void*)(uint32_t)(uintptr_t)l,
      16, 0, 0);
}

__device__ __forceinline__ f32x16 mfma32(bf16x8 a, bf16x8 b, f32x16 c) {
  return __builtin_amdgcn_mfma_f32_32x32x16_bf16(a, b, c, 0, 0, 0);
}
__device__ __forceinline__ f32x4 mfma16(bf16x8 a, bf16x8 b, f32x4 c) {
  return __builtin_amdgcn_mfma_f32_16x16x32_bf16(a, b, c, 0, 0, 0);
}

// ---------------- fp32 -> bf16 conversion of x, Wq, Wk, Wv, Wo ----------------
// Grid-stride (G11): 2048 blocks x 256 thr, exactly 6 float4s per thread
// (3,145,728 total), uniform loop with zero tail divergence.
__global__ void convert_all(const float* __restrict__ x, const float* __restrict__ wq,
                            const float* __restrict__ wk, const float* __restrict__ wv,
                            const float* __restrict__ wo, ushort* __restrict__ o) {
  const long NX = 2097152;   // x float4s
  const long NW = 262144;    // per-W float4s
  const long total = NX + 4 * NW;
  const long stride = (long)gridDim.x * 256;
  for (long i = (long)blockIdx.x * 256 + threadIdx.x; i < total; i += stride) {
    const float4* s;
    long off;
    if (i < NX) { s = (const float4*)x; off = i; }
    else {
      long j = i - NX;
      int wsel = (int)(j >> 18);
      off = j & (NW - 1);
      s = (const float4*)(wsel == 0 ? wq : wsel == 1 ? wk : wsel == 2 ? wv : wo);
    }
    float4 v = s[off];
    ushort4 r;
    r.x = f2bf(v.x); r.y = f2bf(v.y); r.z = f2bf(v.z); r.w = f2bf(v.w);
    ((ushort4*)o)[i] = r;
  }
}

// ---------------- GEMM: C[m,n] = sum_k A[m,k] * B[n,k]  (B^T layout) ----------------
// Round-19 proven best: dbuf LDS, one __syncthreads/K-step, __launch_bounds__(256,4),
// vectorized V-transposed store, bijective XCD swizzle. 68.4 us on QKV (754 TF).
// MODE 0: A=x_bf16; B in {Wq,Wk,Wv}; Q pre-scaled by QSCALE; V stored [B,H,DK,L].
// MODE 1: A=attnout; B=Wo; out fp32 [8192,1024]
template<int MODE>
__global__ __launch_bounds__(256, 4)
void gemm_bt(const ushort* __restrict__ A,
             const ushort* __restrict__ Bq, const ushort* __restrict__ Bk, const ushort* __restrict__ Bv,
             ushort* __restrict__ Oq, ushort* __restrict__ Ok, ushort* __restrict__ Ov,
             float* __restrict__ OF) {
  __shared__ __align__(16) ushort lA[2][128 * 32];
  __shared__ __align__(16) ushort lB[2][128 * 32];
  const int t = threadIdx.x;
  const int w = t >> 6, l = t & 63;
  const int lr = l & 15, lh = l >> 4;
  const int bxr = blockIdx.x;
  const int bx = (bxr & 7) * 8 + (bxr >> 3);
  const int m0 = bx * 128;
  const int ng = blockIdx.y * 128;
  const ushort* Bp;
  ushort* Op = nullptr;
  int mi = 0, n0;
  if (MODE == 0) {
    mi = ng >> 10;
    Bp = (mi == 0) ? Bq : (mi == 1) ? Bk : Bv;
    Op = (mi == 0) ? Oq : (mi == 1) ? Ok : Ov;
    n0 = ng & 1023;
  } else {
    Bp = Bq;
    n0 = ng;
  }
  const int wrow = (w >> 1) * 64, wcol = (w & 1) * 64;
  const int r = t >> 2, c = t & 3;
  const ushort* gA0 = A + (size_t)(m0 + r) * ND + c * 8;
  const ushort* gA1 = A + (size_t)(m0 + 64 + r) * ND + c * 8;
  const ushort* gB0 = Bp + (size_t)(n0 + r) * ND + c * 8;
  const ushort* gB1 = Bp + (size_t)(n0 + 64 + r) * ND + c * 8;

#define GSTAGE(bi, kofs) do {                              \
    gload16(gA0 + (kofs), &lA[bi][w * 512]);               \
    gload16(gA1 + (kofs), &lA[bi][2048 + w * 512]);        \
    gload16(gB0 + (kofs), &lB[bi][w * 512]);               \
    gload16(gB1 + (kofs), &lB[bi][2048 + w * 512]);        \
  } while (0)

  GSTAGE(0, 0);
  f32x4 acc[4][4] = {};
  for (int kt = 0; kt < ND; kt += 32) {
    const int buf = (kt >> 5) & 1;
    __syncthreads();                       // stage(kt) complete; compute(kt-1) closed
    if (kt + 32 < ND) GSTAGE(buf ^ 1, kt + 32);
    bf16x8 af[4], bfr[4];
#pragma unroll
    for (int mt = 0; mt < 4; mt++)
      af[mt] = *(const bf16x8*)&lA[buf][(wrow + mt * 16 + lr) * 32 + lh * 8];
#pragma unroll
    for (int nt = 0; nt < 4; nt++)
      bfr[nt] = *(const bf16x8*)&lB[buf][(wcol + nt * 16 + lr) * 32 + lh * 8];
#pragma unroll
    for (int mt = 0; mt < 4; mt++)
#pragma unroll
      for (int nt = 0; nt < 4; nt++)
        acc[mt][nt] = mfma16(af[mt], bfr[nt], acc[mt][nt]);
  }
#undef GSTAGE
  // epilogue: C/D layout col = lane&15, row = (lane>>4)*4 + reg
#pragma unroll
  for (int mt = 0; mt < 4; mt++) {
#pragma unroll
    for (int nt = 0; nt < 4; nt++) {
      if (MODE == 0 && mi == 2) {
        // V stored transposed [B,H,DK,L]: j indexes consecutive ll -> ushort4 store
        int m = m0 + wrow + mt * 16 + lh * 4;
        int nl = n0 + wcol + nt * 16 + lr;
        int b = m >> 11, ll = m & 2047;
        int h = nl >> 6, dk = nl & 63;
        ushort4 vs;
        vs.x = f2bf(acc[mt][nt][0]); vs.y = f2bf(acc[mt][nt][1]);
        vs.z = f2bf(acc[mt][nt][2]); vs.w = f2bf(acc[mt][nt][3]);
        *(ushort4*)&Op[(((size_t)(b * NH + h)) * NDK + dk) * NL + ll] = vs;
      } else {
#pragma unroll
        for (int j = 0; j < 4; j++) {
          int m = m0 + wrow + mt * 16 + lh * 4 + j;
          int n = wcol + nt * 16 + lr;
          if (MODE == 0) {
            int nl = n0 + n;
            int b = m >> 11, ll = m & 2047;
            int h = nl >> 6, dk = nl & 63;
            float v = acc[mt][nt][j];
            if (mi == 0) v *= QSCALE;   // fold softmax scale+log2e into Q
            Op[(((size_t)(b * NH + h)) * NL + ll) * NDK + dk] = f2bf(v);
          } else {
            OF[(size_t)m * ND + ng + n] = acc[mt][nt][j];
          }
        }
      }
    }
  }
}

// ---------------- causal flash attention, 4-wave, 3-deep K/V ring ----------------
// Round-17/19 kernel, byte-identical (counted vmcnt pipeline, no-max exp2 softmax,
// MFMA denominator, permlane32_swap P-pack, diagonal half-skip, LPT). ~55 us.
__global__ __launch_bounds__(256, 3)
void attn_fwd(const ushort* __restrict__ Q, const ushort* __restrict__ Kg,
              const ushort* __restrict__ VT, ushort* __restrict__ O) {
  __shared__ __align__(16) ushort lK[3][64 * 64];   // [kv][d], swizzled chunks
  __shared__ __align__(16) ushort lV[3][64 * 64];   // [dk][kv], swizzled chunks
  const int t = threadIdx.x;
  const int w = t >> 6, l = t & 63;
  const int l31 = l & 31, hi = l >> 5;
  const int id = blockIdx.x;
  const int bh = id & 63;                 // bh fastest -> bh%8 pins XCD (K/V L2 affinity)
  const int qt = 15 - (id >> 6);          // LPT: longest q-tiles dispatch first
  const size_t base = (size_t)bh * (NL * NDK);
  const int q0w = qt * 128 + w * 32;
  const int ktmax = q0w >> 6;
  const int NT = qt * 2 + 2;

  bf16x8 qf[4];
  {
    const ushort* qp = Q + base + (size_t)(q0w + l31) * NDK + hi * 8;
#pragma unroll
    for (int sl = 0; sl < 4; sl++) qf[sl] = *(const bf16x8*)(qp + sl * 16);
  }
  bf16x8 ones;
#pragma unroll
  for (int r = 0; r < 8; r++) ones[r] = (short)0x3F80;

  const int kr0 = t >> 3, kc0 = (t & 7) ^ (kr0 & 7);
  const int s1i = t + 256;
  const int kr1 = s1i >> 3, kc1 = (s1i & 7) ^ (kr1 & 7);
  const ushort* gK0 = Kg + base + (size_t)kr0 * NDK + kc0 * 8;
  const ushort* gK1 = Kg + base + (size_t)kr1 * NDK + kc1 * 8;
  const ushort* gV0 = VT + base + (size_t)kr0 * NL + kc0 * 8;
  const ushort* gV1 = VT + base + (size_t)kr1 * NL + kc1 * 8;

  f32x16 accO0 = {}, accO1 = {}, accS = {};
  const int swz = l31 & 7;

#define PACKPAIR(sv, plo, phi) do {                                          \
    unsigned int a0 = cvtpk(sv[0], sv[1]),   a1 = cvtpk(sv[2], sv[3]);       \
    unsigned int b0 = cvtpk(sv[4], sv[5]),   b1 = cvtpk(sv[6], sv[7]);       \
    unsigned int c0 = cvtpk(sv[8], sv[9]),   c1 = cvtpk(sv[10], sv[11]);     \
    unsigned int d0 = cvtpk(sv[12], sv[13]), d1 = cvtpk(sv[14], sv[15]);     \
    asm("v_permlane32_swap_b32 %0, %1" : "+v"(a0), "+v"(b0));                \
    asm("v_permlane32_swap_b32 %0, %1" : "+v"(a1), "+v"(b1));                \
    asm("v_permlane32_swap_b32 %0, %1" : "+v"(c0), "+v"(d0));                \
    asm("v_permlane32_swap_b32 %0, %1" : "+v"(c1), "+v"(d1));                \
    uint4v lo_; lo_[0] = a0; lo_[1] = a1; lo_[2] = b0; lo_[3] = b1;          \
    uint4v hi_; hi_[0] = c0; hi_[1] = c1; hi_[2] = d0; hi_[3] = d1;          \
    plo = __builtin_bit_cast(bf16x8, lo_);                                   \
    phi = __builtin_bit_cast(bf16x8, hi_);                                   \
  } while (0)

#define STAGE(slot, kt1) do {                                       \
    const size_t kvn = (size_t)(kt1) * 64;                          \
    gload16(gK0 + kvn * NDK, &lK[slot][w * 512]);                   \
    gload16(gK1 + kvn * NDK, &lK[slot][2048 + w * 512]);            \
    gload16(gV0 + kvn, &lV[slot][w * 512]);                         \
    gload16(gV1 + kvn, &lV[slot][2048 + w * 512]);                  \
  } while (0)

  STAGE(0, 0);
  STAGE(1, 1);

  int scur = 0, snxt = 2;
  for (int kt = 0; kt < NT; kt++) {
    if (kt + 1 < NT) asm volatile("s_waitcnt vmcnt(4)" ::: "memory");
    else             asm volatile("s_waitcnt vmcnt(0)" ::: "memory");
    __builtin_amdgcn_s_barrier();
    __builtin_amdgcn_sched_barrier(0);
    if (kt + 2 < NT) STAGE(snxt, kt + 2);
    if (kt <= ktmax) {
      const ushort* bK = lK[scur];
      const ushort* bV = lV[scur];
      const bool dtile = (kt == ktmax);
      const bool skipHi = dtile && !(w & 1);  // even waves: s1 half fully masked
      f32x16 s0 = {}, s1v = {};
      __builtin_amdgcn_s_setprio(1);
#pragma unroll
      for (int sl = 0; sl < 4; sl++) {
        int c = 2 * sl + hi;
        bf16x8 kf0 = *(const bf16x8*)&bK[l31 * 64 + ((c ^ swz) * 8)];
        s0 = mfma32(kf0, qf[sl], s0);
      }
      if (!skipHi) {
#pragma unroll
        for (int sl = 0; sl < 4; sl++) {
          int c = 2 * sl + hi;
          bf16x8 kf1 = *(const bf16x8*)&bK[(32 + l31) * 64 + ((c ^ swz) * 8)];
          s1v = mfma32(kf1, qf[sl], s1v);
        }
      }
      __builtin_amdgcn_s_setprio(0);
      if (dtile) {
        if (!(w & 1)) {
#pragma unroll
          for (int r = 0; r < 16; r++) {
            int kvo = (r & 3) + 8 * (r >> 2) + 4 * hi;
            if (kvo > l31) s0[r] = -1e30f;
          }
        } else {
#pragma unroll
          for (int r = 0; r < 16; r++) {
            int kvo = (r & 3) + 8 * (r >> 2) + 4 * hi;
            if (kvo > l31) s1v[r] = -1e30f;
          }
        }
      }
#pragma unroll
      for (int r = 0; r < 16; r++) s0[r] = exp2f(s0[r]);
      if (!skipHi) {
#pragma unroll
        for (int r = 0; r < 16; r++) s1v[r] = exp2f(s1v[r]);
      }
      bf16x8 pa[4];
      PACKPAIR(s0, pa[0], pa[1]);
      if (!skipHi) PACKPAIR(s1v, pa[2], pa[3]);
      __builtin_amdgcn_s_setprio(1);
#pragma unroll
      for (int ks = 0; ks < 2; ks++) {
        int c = 2 * ks + hi;
        bf16x8 vf0 = *(const bf16x8*)&bV[l31 * 64 + ((c ^ swz) * 8)];
        bf16x8 vf1 = *(const bf16x8*)&bV[(32 + l31) * 64 + ((c ^ swz) * 8)];
        accO0 = mfma32(vf0, pa[ks], accO0);
        accO1 = mfma32(vf1, pa[ks], accO1);
        accS = mfma32(ones, pa[ks], accS);
      }
      if (!skipHi) {
#pragma unroll
        for (int ks = 2; ks < 4; ks++) {
          int c = 2 * ks + hi;
          bf16x8 vf0 = *(const bf16x8*)&bV[l31 * 64 + ((c ^ swz) * 8)];
          bf16x8 vf1 = *(const bf16x8*)&bV[(32 + l31) * 64 + ((c ^ swz) * 8)];
          accO0 = mfma32(vf0, pa[ks], accO0);
          accO1 = mfma32(vf1, pa[ks], accO1);
          accS = mfma32(ones, pa[ks], accS);
        }
      }
      __builtin_amdgcn_s_setprio(0);
    }
    scur = (scur + 1 == 3) ? 0 : scur + 1;
    snxt = (snxt + 1 == 3) ? 0 : snxt + 1;
  }
#undef STAGE
#undef PACKPAIR
  const int b = bh >> 4, h = bh & 15;
  const float inv = 1.0f / accS[0];
  const int q = q0w + l31;
  ushort* orow = O + ((size_t)b * NL + q) * ND + h * NDK;
#pragma unroll
  for (int gi = 0; gi < 4; gi++) {
    ushort4 o0, o1;
    o0.x = f2bf(accO0[4 * gi + 0] * inv); o0.y = f2bf(accO0[4 * gi + 1] * inv);
    o0.z = f2bf(accO0[4 * gi + 2] * inv); o0.w = f2bf(accO0[4 * gi + 3] * inv);
    o1.x = f2bf(accO1[4 * gi + 0] * inv); o1.y = f2bf(accO1[4 * gi + 1] * inv);
    o1.z = f2bf(accO1[4 * gi + 2] * inv); o1.w = f2bf(accO1[4 * gi + 3] * inv);
    *(ushort4*)&orow[8 * gi + 4 * hi] = o0;
    *(ushort4*)&orow[32 + 8 * gi + 4 * hi] = o1;
  }
}

extern "C" void kernel_launch(void* const* d_in, const int* in_sizes, int n_in,
                              void* d_out, int out_size, void* d_ws, size_t ws_size,
                              hipStream_t stream) {
  const float* x = (const float*)d_in[0];
  const float* wq = (const float*)d_in[1];
  const float* wk = (const float*)d_in[2];
  const float* wv = (const float*)d_in[3];
  const float* wo = (const float*)d_in[4];
  char* ws = (char*)d_ws;
  ushort* xb  = (ushort*)(ws);               // 16,777,216 B
  ushort* wqb = (ushort*)(ws + 16777216);
  ushort* wkb = (ushort*)(ws + 18874368);
  ushort* wvb = (ushort*)(ws + 20971520);
  ushort* wob = (ushort*)(ws + 23068672);
  ushort* Qb  = (ushort*)(ws + 25165824);    // [B,H,L,DK] bf16, pre-scaled
  ushort* Kb  = (ushort*)(ws + 41943040);    // [B,H,L,DK]
  ushort* Vb  = (ushort*)(ws + 58720256);    // [B,H,DK,L] (transposed)
  ushort* Ob  = (ushort*)(ws + 75497472);    // [B,L,D] bf16

  convert_all<<<2048, 256, 0, stream>>>(x, wq, wk, wv, wo, xb);
  gemm_bt<0><<<dim3(64, 24), 256, 0, stream>>>(xb, wqb, wkb, wvb, Qb, Kb, Vb, nullptr);
  attn_fwd<<<dim3(1024), 256, 0, stream>>>(Qb, Kb, Vb, Ob);
  gemm_bt<1><<<dim3(64, 8), 256, 0, stream>>>(Ob, wob, nullptr, nullptr,
                                              nullptr, nullptr, nullptr, (float*)d_out);
}

// Round 24
// 155.808 us; speedup vs baseline: 1.0066x; 1.0066x over previous
//
#include <hip/hip_runtime.h>
#include <hip/hip_bf16.h>
#include <stdint.h>

typedef short bf16x8 __attribute__((ext_vector_type(8)));
typedef float f32x4 __attribute__((ext_vector_type(4)));
typedef float f32x16 __attribute__((ext_vector_type(16)));
typedef unsigned int uint4v __attribute__((ext_vector_type(4)));

#define NB 4
#define NL 2048
#define ND 1024
#define NH 16
#define NDK 64
#define NM (NB*NL)
// 1/sqrt(DK) * log2(e): folded into Q at the QKV-GEMM epilogue -> softmax in exp2 domain
#define QSCALE 0.18033688011112042f

__device__ __forceinline__ ushort f2bf(float f) {
  __bf16 h = (__bf16)f;
  return __builtin_bit_cast(unsigned short, h);
}

__device__ __forceinline__ unsigned int cvtpk(float lo, float hi) {
  unsigned int d;
  asm("v_cvt_pk_bf16_f32 %0, %1, %2" : "=v"(d) : "v"(lo), "v"(hi));
  return d;
}

// async global->LDS, 16B per lane. lds base must be wave-uniform; HW adds lane*16.
__device__ __forceinline__ void gload16(const void* g, void* l) {
  __builtin_amdgcn_global_load_lds(
      (__attribute__((address_space(1))) void*)(uintptr_t)g,
      (__attribute__((address_space(3))) void*)(uint32_t)(uintptr_t)l,
      16, 0, 0);
}

__device__ __forceinline__ f32x16 mfma32(bf16x8 a, bf16x8 b, f32x16 c) {
  return __builtin_amdgcn_mfma_f32_32x32x16_bf16(a, b, c, 0, 0, 0);
}
__device__ __forceinline__ f32x4 mfma16(bf16x8 a, bf16x8 b, f32x4 c) {
  return __builtin_amdgcn_mfma_f32_16x16x32_bf16(a, b, c, 0, 0, 0);
}

// ---------------- fp32 -> bf16 conversion of x, Wq, Wk, Wv, Wo ----------------
__global__ void convert_all(const float* __restrict__ x, const float* __restrict__ wq,
                            const float* __restrict__ wk, const float* __restrict__ wv,
                            const float* __restrict__ wo, ushort* __restrict__ o) {
  long i = (long)blockIdx.x * 256 + threadIdx.x;   // float4 index
  const long NX = 2097152;   // x float4s
  const long NW = 262144;    // per-W float4s
  const float4* s;
  long off;
  if (i < NX) { s = (const float4*)x; off = i; }
  else {
    long j = i - NX;
    int wsel = (int)(j >> 18);
    off = j & (NW - 1);
    s = (const float4*)(wsel == 0 ? wq : wsel == 1 ? wk : wsel == 2 ? wv : wo);
  }
  float4 v = s[off];
  ushort4 r;
  r.x = f2bf(v.x); r.y = f2bf(v.y); r.z = f2bf(v.z); r.w = f2bf(v.w);
  ((ushort4*)o)[i] = r;
}

// ---------------- GEMM: C[m,n] = sum_k A[m,k] * B[n,k]  (B^T layout) ----------------
// Session-best proven: dbuf LDS, one __syncthreads/K-step, __launch_bounds__(256,4),
// vectorized V-transposed store, bijective XCD swizzle. 68.3 us on QKV (754 TF).
// MODE 0: A=x_bf16; B in {Wq,Wk,Wv}; Q pre-scaled by QSCALE; V stored [B,H,DK,L].
// MODE 1: A=attnout; B=Wo; out fp32 [8192,1024]
template<int MODE>
__global__ __launch_bounds__(256, 4)
void gemm_bt(const ushort* __restrict__ A,
             const ushort* __restrict__ Bq, const ushort* __restrict__ Bk, const ushort* __restrict__ Bv,
             ushort* __restrict__ Oq, ushort* __restrict__ Ok, ushort* __restrict__ Ov,
             float* __restrict__ OF) {
  __shared__ __align__(16) ushort lA[2][128 * 32];
  __shared__ __align__(16) ushort lB[2][128 * 32];
  const int t = threadIdx.x;
  const int w = t >> 6, l = t & 63;
  const int lr = l & 15, lh = l >> 4;
  const int bxr = blockIdx.x;
  const int bx = (bxr & 7) * 8 + (bxr >> 3);
  const int m0 = bx * 128;
  const int ng = blockIdx.y * 128;
  const ushort* Bp;
  ushort* Op = nullptr;
  int mi = 0, n0;
  if (MODE == 0) {
    mi = ng >> 10;
    Bp = (mi == 0) ? Bq : (mi == 1) ? Bk : Bv;
    Op = (mi == 0) ? Oq : (mi == 1) ? Ok : Ov;
    n0 = ng & 1023;
  } else {
    Bp = Bq;
    n0 = ng;
  }
  const int wrow = (w >> 1) * 64, wcol = (w & 1) * 64;
  const int r = t >> 2, c = t & 3;
  const ushort* gA0 = A + (size_t)(m0 + r) * ND + c * 8;
  const ushort* gA1 = A + (size_t)(m0 + 64 + r) * ND + c * 8;
  const ushort* gB0 = Bp + (size_t)(n0 + r) * ND + c * 8;
  const ushort* gB1 = Bp + (size_t)(n0 + 64 + r) * ND + c * 8;

#define GSTAGE(bi, kofs) do {                              \
    gload16(gA0 + (kofs), &lA[bi][w * 512]);               \
    gload16(gA1 + (kofs), &lA[bi][2048 + w * 512]);        \
    gload16(gB0 + (kofs), &lB[bi][w * 512]);               \
    gload16(gB1 + (kofs), &lB[bi][2048 + w * 512]);        \
  } while (0)

  GSTAGE(0, 0);
  f32x4 acc[4][4] = {};
  for (int kt = 0; kt < ND; kt += 32) {
    const int buf = (kt >> 5) & 1;
    __syncthreads();                       // stage(kt) complete; compute(kt-1) closed
    if (kt + 32 < ND) GSTAGE(buf ^ 1, kt + 32);
    bf16x8 af[4], bfr[4];
#pragma unroll
    for (int mt = 0; mt < 4; mt++)
      af[mt] = *(const bf16x8*)&lA[buf][(wrow + mt * 16 + lr) * 32 + lh * 8];
#pragma unroll
    for (int nt = 0; nt < 4; nt++)
      bfr[nt] = *(const bf16x8*)&lB[buf][(wcol + nt * 16 + lr) * 32 + lh * 8];
#pragma unroll
    for (int mt = 0; mt < 4; mt++)
#pragma unroll
      for (int nt = 0; nt < 4; nt++)
        acc[mt][nt] = mfma16(af[mt], bfr[nt], acc[mt][nt]);
  }
#undef GSTAGE
  // epilogue: C/D layout col = lane&15, row = (lane>>4)*4 + reg
#pragma unroll
  for (int mt = 0; mt < 4; mt++) {
#pragma unroll
    for (int nt = 0; nt < 4; nt++) {
      if (MODE == 0 && mi == 2) {
        // V stored transposed [B,H,DK,L]: j indexes consecutive ll -> ushort4 store
        int m = m0 + wrow + mt * 16 + lh * 4;
        int nl = n0 + wcol + nt * 16 + lr;
        int b = m >> 11, ll = m & 2047;
        int h = nl >> 6, dk = nl & 63;
        ushort4 vs;
        vs.x = f2bf(acc[mt][nt][0]); vs.y = f2bf(acc[mt][nt][1]);
        vs.z = f2bf(acc[mt][nt][2]); vs.w = f2bf(acc[mt][nt][3]);
        *(ushort4*)&Op[(((size_t)(b * NH + h)) * NDK + dk) * NL + ll] = vs;
      } else {
#pragma unroll
        for (int j = 0; j < 4; j++) {
          int m = m0 + wrow + mt * 16 + lh * 4 + j;
          int n = wcol + nt * 16 + lr;
          if (MODE == 0) {
            int nl = n0 + n;
            int b = m >> 11, ll = m & 2047;
            int h = nl >> 6, dk = nl & 63;
            float v = acc[mt][nt][j];
            if (mi == 0) v *= QSCALE;   // fold softmax scale+log2e into Q
            Op[(((size_t)(b * NH + h)) * NL + ll) * NDK + dk] = f2bf(v);
          } else {
            OF[(size_t)m * ND + ng + n] = acc[mt][nt][j];
          }
        }
      }
    }
  }
}

// ---------------- causal flash attention, 4-wave, 3-deep K/V ring ----------------
// Session-best proven (~55 us): counted vmcnt(4) pipeline + raw barrier (T4), 3-slot
// LDS ring, no-max exp2 softmax (Q pre-scaled), denominator on the matrix pipe
// (accS += ones x P), permlane32_swap P-pack, diagonal half-skip, LPT work map,
// bh%8 -> XCD L2 affinity.
__global__ __launch_bounds__(256, 3)
void attn_fwd(const ushort* __restrict__ Q, const ushort* __restrict__ Kg,
              const ushort* __restrict__ VT, ushort* __restrict__ O) {
  __shared__ __align__(16) ushort lK[3][64 * 64];   // [kv][d], swizzled chunks
  __shared__ __align__(16) ushort lV[3][64 * 64];   // [dk][kv], swizzled chunks
  const int t = threadIdx.x;
  const int w = t >> 6, l = t & 63;
  const int l31 = l & 31, hi = l >> 5;
  const int id = blockIdx.x;
  const int bh = id & 63;
  const int qt = 15 - (id >> 6);          // LPT: longest q-tiles dispatch first
  const size_t base = (size_t)bh * (NL * NDK);
  const int q0w = qt * 128 + w * 32;
  const int ktmax = q0w >> 6;
  const int NT = qt * 2 + 2;

  bf16x8 qf[4];
  {
    const ushort* qp = Q + base + (size_t)(q0w + l31) * NDK + hi * 8;
#pragma unroll
    for (int sl = 0; sl < 4; sl++) qf[sl] = *(const bf16x8*)(qp + sl * 16);
  }
  bf16x8 ones;
#pragma unroll
  for (int r = 0; r < 8; r++) ones[r] = (short)0x3F80;

  const int kr0 = t >> 3, kc0 = (t & 7) ^ (kr0 & 7);
  const int s1i = t + 256;
  const int kr1 = s1i >> 3, kc1 = (s1i & 7) ^ (kr1 & 7);
  const ushort* gK0 = Kg + base + (size_t)kr0 * NDK + kc0 * 8;
  const ushort* gK1 = Kg + base + (size_t)kr1 * NDK + kc1 * 8;
  const ushort* gV0 = VT + base + (size_t)kr0 * NL + kc0 * 8;
  const ushort* gV1 = VT + base + (size_t)kr1 * NL + kc1 * 8;

  f32x16 accO0 = {}, accO1 = {}, accS = {};
  const int swz = l31 & 7;

#define PACKPAIR(sv, plo, phi) do {                                          \
    unsigned int a0 = cvtpk(sv[0], sv[1]),   a1 = cvtpk(sv[2], sv[3]);       \
    unsigned int b0 = cvtpk(sv[4], sv[5]),   b1 = cvtpk(sv[6], sv[7]);       \
    unsigned int c0 = cvtpk(sv[8], sv[9]),   c1 = cvtpk(sv[10], sv[11]);     \
    unsigned int d0 = cvtpk(sv[12], sv[13]), d1 = cvtpk(sv[14], sv[15]);     \
    asm("v_permlane32_swap_b32 %0, %1" : "+v"(a0), "+v"(b0));                \
    asm("v_permlane32_swap_b32 %0, %1" : "+v"(a1), "+v"(b1));                \
    asm("v_permlane32_swap_b32 %0, %1" : "+v"(c0), "+v"(d0));                \
    asm("v_permlane32_swap_b32 %0, %1" : "+v"(c1), "+v"(d1));                \
    uint4v lo_; lo_[0] = a0; lo_[1] = a1; lo_[2] = b0; lo_[3] = b1;          \
    uint4v hi_; hi_[0] = c0; hi_[1] = c1; hi_[2] = d0; hi_[3] = d1;          \
    plo = __builtin_bit_cast(bf16x8, lo_);                                   \
    phi = __builtin_bit_cast(bf16x8, hi_);                                   \
  } while (0)

#define STAGE(slot, kt1) do {                                       \
    const size_t kvn = (size_t)(kt1) * 64;                          \
    gload16(gK0 + kvn * NDK, &lK[slot][w * 512]);                   \
    gload16(gK1 + kvn * NDK, &lK[slot][2048 + w * 512]);            \
    gload16(gV0 + kvn, &lV[slot][w * 512]);                         \
    gload16(gV1 + kvn, &lV[slot][2048 + w * 512]);                  \
  } while (0)

  STAGE(0, 0);
  STAGE(1, 1);

  int scur = 0, snxt = 2;
  for (int kt = 0; kt < NT; kt++) {
    if (kt + 1 < NT) asm volatile("s_waitcnt vmcnt(4)" ::: "memory");
    else             asm volatile("s_waitcnt vmcnt(0)" ::: "memory");
    __builtin_amdgcn_s_barrier();
    __builtin_amdgcn_sched_barrier(0);
    if (kt + 2 < NT) STAGE(snxt, kt + 2);
    if (kt <= ktmax) {
      const ushort* bK = lK[scur];
      const ushort* bV = lV[scur];
      const bool dtile = (kt == ktmax);
      const bool skipHi = dtile && !(w & 1);  // even waves: s1 half fully masked
      f32x16 s0 = {}, s1v = {};
      __builtin_amdgcn_s_setprio(1);
#pragma unroll
      for (int sl = 0; sl < 4; sl++) {
        int c = 2 * sl + hi;
        bf16x8 kf0 = *(const bf16x8*)&bK[l31 * 64 + ((c ^ swz) * 8)];
        s0 = mfma32(kf0, qf[sl], s0);
      }
      if (!skipHi) {
#pragma unroll
        for (int sl = 0; sl < 4; sl++) {
          int c = 2 * sl + hi;
          bf16x8 kf1 = *(const bf16x8*)&bK[(32 + l31) * 64 + ((c ^ swz) * 8)];
          s1v = mfma32(kf1, qf[sl], s1v);
        }
      }
      __builtin_amdgcn_s_setprio(0);
      if (dtile) {
        if (!(w & 1)) {
#pragma unroll
          for (int r = 0; r < 16; r++) {
            int kvo = (r & 3) + 8 * (r >> 2) + 4 * hi;
            if (kvo > l31) s0[r] = -1e30f;
          }
        } else {
#pragma unroll
          for (int r = 0; r < 16; r++) {
            int kvo = (r & 3) + 8 * (r >> 2) + 4 * hi;
            if (kvo > l31) s1v[r] = -1e30f;
          }
        }
      }
#pragma unroll
      for (int r = 0; r < 16; r++) s0[r] = exp2f(s0[r]);
      if (!skipHi) {
#pragma unroll
        for (int r = 0; r < 16; r++) s1v[r] = exp2f(s1v[r]);
      }
      bf16x8 pa[4];
      PACKPAIR(s0, pa[0], pa[1]);
      if (!skipHi) PACKPAIR(s1v, pa[2], pa[3]);
      __builtin_amdgcn_s_setprio(1);
#pragma unroll
      for (int ks = 0; ks < 2; ks++) {
        int c = 2 * ks + hi;
        bf16x8 vf0 = *(const bf16x8*)&bV[l31 * 64 + ((c ^ swz) * 8)];
        bf16x8 vf1 = *(const bf16x8*)&bV[(32 + l31) * 64 + ((c ^ swz) * 8)];
        accO0 = mfma32(vf0, pa[ks], accO0);
        accO1 = mfma32(vf1, pa[ks], accO1);
        accS = mfma32(ones, pa[ks], accS);
      }
      if (!skipHi) {
#pragma unroll
        for (int ks = 2; ks < 4; ks++) {
          int c = 2 * ks + hi;
          bf16x8 vf0 = *(const bf16x8*)&bV[l31 * 64 + ((c ^ swz) * 8)];
          bf16x8 vf1 = *(const bf16x8*)&bV[(32 + l31) * 64 + ((c ^ swz) * 8)];
          accO0 = mfma32(vf0, pa[ks], accO0);
          accO1 = mfma32(vf1, pa[ks], accO1);
          accS = mfma32(ones, pa[ks], accS);
        }
      }
      __builtin_amdgcn_s_setprio(0);
    }
    scur = (scur + 1 == 3) ? 0 : scur + 1;
    snxt = (snxt + 1 == 3) ? 0 : snxt + 1;
  }
#undef STAGE
#undef PACKPAIR
  const int b = bh >> 4, h = bh & 15;
  const float inv = 1.0f / accS[0];
  const int q = q0w + l31;
  ushort* orow = O + ((size_t)b * NL + q) * ND + h * NDK;
#pragma unroll
  for (int gi = 0; gi < 4; gi++) {
    ushort4 o0, o1;
    o0.x = f2bf(accO0[4 * gi + 0] * inv); o0.y = f2bf(accO0[4 * gi + 1] * inv);
    o0.z = f2bf(accO0[4 * gi + 2] * inv); o0.w = f2bf(accO0[4 * gi + 3] * inv);
    o1.x = f2bf(accO1[4 * gi + 0] * inv); o1.y = f2bf(accO1[4 * gi + 1] * inv);
    o1.z = f2bf(accO1[4 * gi + 2] * inv); o1.w = f2bf(accO1[4 * gi + 3] * inv);
    *(ushort4*)&orow[8 * gi + 4 * hi] = o0;
    *(ushort4*)&orow[32 + 8 * gi + 4 * hi] = o1;
  }
}

extern "C" void kernel_launch(void* const* d_in, const int* in_sizes, int n_in,
                              void* d_out, int out_size, void* d_ws, size_t ws_size,
                              hipStream_t stream) {
  const float* x = (const float*)d_in[0];
  const float* wq = (const float*)d_in[1];
  const float* wk = (const float*)d_in[2];
  const float* wv = (const float*)d_in[3];
  const float* wo = (const float*)d_in[4];
  char* ws = (char*)d_ws;
  ushort* xb  = (ushort*)(ws);               // 16,777,216 B
  ushort* wqb = (ushort*)(ws + 16777216);
  ushort* wkb = (ushort*)(ws + 18874368);
  ushort* wvb = (ushort*)(ws + 20971520);
  ushort* wob = (ushort*)(ws + 23068672);
  ushort* Qb  = (ushort*)(ws + 25165824);    // [B,H,L,DK] bf16, pre-scaled
  ushort* Kb  = (ushort*)(ws + 41943040);    // [B,H,L,DK]
  ushort* Vb  = (ushort*)(ws + 58720256);    // [B,H,DK,L] (transposed)
  ushort* Ob  = (ushort*)(ws + 75497472);    // [B,L,D] bf16

  convert_all<<<12288, 256, 0, stream>>>(x, wq, wk, wv, wo, xb);
  gemm_bt<0><<<dim3(64, 24), 256, 0, stream>>>(xb, wqb, wkb, wvb, Qb, Kb, Vb, nullptr);
  attn_fwd<<<dim3(1024), 256, 0, stream>>>(Qb, Kb, Vb, Ob);
  gemm_bt<1><<<dim3(64, 8), 256, 0, stream>>>(Ob, wob, nullptr, nullptr,
                                              nullptr, nullptr, nullptr, (float*)d_out);
}